// Round 10
// baseline (244.109 us; speedup 1.0000x reference)
//
#include <hip/hip_runtime.h>

#define VOXELS   884736      // 96^3
#define OUT_CAM  0
#define OUT_PSE  23003136    // 2*13*VOXELS
#define OUT_MSK  24772608
#define OUT_LOG  26542080

// ws layout (floats)
#define WS_WT 0              // wt2[27][128][256]  (884736)
#define WS_P  884736         // P[54][2][128][64]  (884736)
#define WS_H1 1769472        // h1[2][128][8]      (2048)

typedef float  f32x4 __attribute__((ext_vector_type(4)));
typedef int    i32x4 __attribute__((ext_vector_type(4)));

// ---------------- CAM + pseudo + updated masks ----------------
// Rounds 1-9: any "one thread owns all 13 planes" schedule = 62 us / 2.5 TB/s
// (29-deep VMEM chain, ~2.7K cy/op queueing-inflated). Fix the STRUCTURE:
// 4 plane-groups x 256 voxel-threads per block. Group g covers planes
// 3g..3g+3 (overlap at 3,6,9 keeps groups uniform; duplicate stores skipped),
// partial argmax merged via LDS with ascending-group strict-> (preserves
// first-max tie-break even on overlapped planes). Per-wave VMEM depth 29->7.
#define CMP(tv, kk)                                             \
  {                                                             \
    if (tv.x > best.x) { best.x = tv.x; bi.x = (kk); }          \
    if (tv.y > best.y) { best.y = tv.y; bi.y = (kk); }          \
    if (tv.z > best.z) { best.z = tv.z; bi.z = (kk); }          \
    if (tv.w > best.w) { best.w = tv.w; bi.w = (kk); }          \
  }

__global__ __launch_bounds__(1024) void k_cam(const float* __restrict__ feat,
                                              const int*   __restrict__ masks,
                                              float* __restrict__ out) {
  __shared__ f32x4 sbv[3][256];
  __shared__ i32x4 sbi[3][256];
  int bx = blockIdx.x;                 // 1728 blocks: 864 per n
  int n  = bx >= 864;
  int t  = threadIdx.x & 255;
  int g  = threadIdx.x >> 8;           // plane-group 0..3 (wave-uniform)
  int q  = (bx - n * 864) * 256 + t;   // quad index < 221184
  int v  = q * 4;
  const float scale = 1.0f / 884736.0f;
  int k0 = g * 3;                      // planes k0..k0+3

  i32x4 m = {0, 0, 0, 0};
  if (g == 0) m = *(const i32x4*)(masks + (size_t)n * VOXELS + v);

  const float* fb = feat + (size_t)(n * 14 + 1) * VOXELS + v;
  f32x4 f0 = *(const f32x4*)(fb + (size_t)(k0 + 0) * VOXELS);
  f32x4 f1 = *(const f32x4*)(fb + (size_t)(k0 + 1) * VOXELS);
  f32x4 f2 = *(const f32x4*)(fb + (size_t)(k0 + 2) * VOXELS);
  f32x4 f3 = *(const f32x4*)(fb + (size_t)(k0 + 3) * VOXELS);

  f32x4 t0 = f0 * scale, t1 = f1 * scale, t2 = f2 * scale, t3 = f3 * scale;
  t0.x = (t0.x > 0.2f) ? t0.x : 0.0f;  t0.y = (t0.y > 0.2f) ? t0.y : 0.0f;
  t0.z = (t0.z > 0.2f) ? t0.z : 0.0f;  t0.w = (t0.w > 0.2f) ? t0.w : 0.0f;
  t1.x = (t1.x > 0.2f) ? t1.x : 0.0f;  t1.y = (t1.y > 0.2f) ? t1.y : 0.0f;
  t1.z = (t1.z > 0.2f) ? t1.z : 0.0f;  t1.w = (t1.w > 0.2f) ? t1.w : 0.0f;
  t2.x = (t2.x > 0.2f) ? t2.x : 0.0f;  t2.y = (t2.y > 0.2f) ? t2.y : 0.0f;
  t2.z = (t2.z > 0.2f) ? t2.z : 0.0f;  t2.w = (t2.w > 0.2f) ? t2.w : 0.0f;
  t3.x = (t3.x > 0.2f) ? t3.x : 0.0f;  t3.y = (t3.y > 0.2f) ? t3.y : 0.0f;
  t3.z = (t3.z > 0.2f) ? t3.z : 0.0f;  t3.w = (t3.w > 0.2f) ? t3.w : 0.0f;

  float* cb = out + OUT_CAM + (size_t)(n * 13) * VOXELS + v;
  if (g == 0)                          // planes 3,6,9 owned by the lower group
    __builtin_nontemporal_store(t0, (f32x4*)(cb + (size_t)(k0 + 0) * VOXELS));
  __builtin_nontemporal_store(t1, (f32x4*)(cb + (size_t)(k0 + 1) * VOXELS));
  __builtin_nontemporal_store(t2, (f32x4*)(cb + (size_t)(k0 + 2) * VOXELS));
  __builtin_nontemporal_store(t3, (f32x4*)(cb + (size_t)(k0 + 3) * VOXELS));

  f32x4 best = t0;
  i32x4 bi = {k0, k0, k0, k0};
  CMP(t1, k0 + 1); CMP(t2, k0 + 2); CMP(t3, k0 + 3);

  if (g) { sbv[g - 1][t] = best; sbi[g - 1][t] = bi; }
  __syncthreads();
  if (g == 0) {
#pragma unroll
    for (int gg = 0; gg < 3; ++gg) {
      f32x4 pb = sbv[gg][t];
      i32x4 pi = sbi[gg][t];
      if (pb.x > best.x) { best.x = pb.x; bi.x = pi.x; }
      if (pb.y > best.y) { best.y = pb.y; bi.y = pi.y; }
      if (pb.z > best.z) { best.z = pb.z; bi.z = pi.z; }
      if (pb.w > best.w) { best.w = pb.w; bi.w = pi.w; }
    }
    f32x4 ps = {(float)bi.x, (float)bi.y, (float)bi.z, (float)bi.w};
    f32x4 um;
    um.x = (m.x == 0) ? ps.x : (float)m.x;
    um.y = (m.y == 0) ? ps.y : (float)m.y;
    um.z = (m.z == 0) ? ps.z : (float)m.z;
    um.w = (m.w == 0) ? ps.w : (float)m.w;
    __builtin_nontemporal_store(ps, (f32x4*)(out + OUT_PSE + (size_t)n * VOXELS + v));
    __builtin_nontemporal_store(um, (f32x4*)(out + OUT_MSK + (size_t)n * VOXELS + v));
  }
}

// ---------------- coalesced transpose: wt2[tap][oc][ic] = w1[oc][ic][tap] ----------------
// view w1 as A[r=(oc,ic)][tap]: rows contiguous -> tile = contiguous 6912-float read
// (staged as 1728 float4 loads, ~7 independent per thread). Also zeroes logits.
__global__ __launch_bounds__(256) void k_trans(const float* __restrict__ w1,
                                               float* __restrict__ wt,
                                               float* __restrict__ logits) {
  __shared__ float s[6912];
  int r0 = blockIdx.x * 256;
  int tid = threadIdx.x;
  if (blockIdx.x == 0 && tid < 2) logits[tid] = 0.0f;
  for (int i = tid; i < 1728; i += 256)
    *(f32x4*)&s[i * 4] = *(const f32x4*)&w1[(size_t)r0 * 27 + i * 4];
  __syncthreads();
#pragma unroll
  for (int tap = 0; tap < 27; ++tap)
    wt[tap * 32768 + r0 + tid] = s[tid * 27 + tap];   // stride 27 coprime 32 banks
}

// ---------------- conv1 split-K partial GEMMs ----------------
// grid 216 = 2n * 27tap * 2ich * 2och ; block computes 64oc x 64pos over 128 ic
#define WSTRIDE 68
__global__ __launch_bounds__(256) void k_conv1(const float* __restrict__ dom,
                                               const float* __restrict__ wt,
                                               float* __restrict__ P) {
  __shared__ float Wl[128 * WSTRIDE];   // [kk][oc'] padded: +4 rotates banks
  __shared__ float Xl[128 * 64];        // [kk][pos]
  int bx = blockIdx.x;
  int och = bx & 1;
  int ich = (bx >> 1) & 1;
  int rest = bx >> 2;              // 0..53
  int tap = rest % 27;
  int n = rest / 27;
  int kd = tap / 9 - 1, kh = (tap % 9) / 3 - 1, kw = tap % 3 - 1;
  int I0 = ich * 128, O0 = och * 64;
  int tid = threadIdx.x;

  // stage W: read wt2[tap][oc][ic] coalesced (float4 over ic), transpose into LDS
  for (int i = tid; i < 2048; i += 256) {
    int oc = i >> 5, k4 = (i & 31) << 2;
    f32x4 rd = *(const f32x4*)&wt[(size_t)(tap * 128 + O0 + oc) * 256 + I0 + k4];
    Wl[(k4 + 0) * WSTRIDE + oc] = rd.x;
    Wl[(k4 + 1) * WSTRIDE + oc] = rd.y;
    Wl[(k4 + 2) * WSTRIDE + oc] = rd.z;
    Wl[(k4 + 3) * WSTRIDE + oc] = rd.w;
  }
  // stage X (shifted, zero-padded)
  for (int i = tid; i < 8192; i += 256) {
    int kk = i >> 6, pos = i & 63;
    int d = pos >> 4, h = (pos >> 2) & 3, w = pos & 3;
    int sd = d + kd, sh = h + kh, sw = w + kw;
    bool ok = ((unsigned)sd < 4u) && ((unsigned)sh < 4u) && ((unsigned)sw < 4u);
    Xl[i] = ok ? dom[((n * 256 + I0 + kk) << 6) + sd * 16 + sh * 4 + sw] : 0.0f;
  }
  __syncthreads();

  int to = tid >> 4, tp = tid & 15;
  f32x4 acc0 = {0, 0, 0, 0}, acc1 = {0, 0, 0, 0}, acc2 = {0, 0, 0, 0}, acc3 = {0, 0, 0, 0};
#pragma unroll 4
  for (int kk = 0; kk < 128; ++kk) {
    f32x4 a = *(f32x4*)&Wl[kk * WSTRIDE + to * 4];
    f32x4 b = *(f32x4*)&Xl[kk * 64 + tp * 4];
    acc0 += a.x * b;
    acc1 += a.y * b;
    acc2 += a.z * b;
    acc3 += a.w * b;
  }
  // P[(tap*2+ich)][n][oc][pos]
  float* pb = P + (size_t)((tap * 2 + ich) * 2 + n) * 8192 + (O0 + to * 4) * 64 + tp * 4;
  *(f32x4*)(pb +   0) = acc0;
  *(f32x4*)(pb +  64) = acc1;
  *(f32x4*)(pb + 128) = acc2;
  *(f32x4*)(pb + 192) = acc3;
}

// ---------------- reduce partials + bias + maxpool2 + relu -> h1[2][128][8] ----------------
// 256 threads: 4 sl-groups x 64 pos
__global__ __launch_bounds__(256) void k_pool1(const float* __restrict__ P,
                                               const float* __restrict__ b1,
                                               float* __restrict__ h1) {
  __shared__ float s[256];
  int n = blockIdx.x >> 7, oc = blockIdx.x & 127;
  int tid = threadIdx.x, pos = tid & 63, sg = tid >> 6;
  float sum = 0.0f;
#pragma unroll
  for (int j = 0; j < 14; ++j) {
    int sl = sg + j * 4;
    if (sl < 54) sum += P[((size_t)(sl * 2 + n) * 128 + oc) * 64 + pos];
  }
  s[tid] = sum;
  __syncthreads();
  if (tid < 64) {
    float tot = b1[oc] + s[pos] + s[64 + pos] + s[128 + pos] + s[192 + pos];
    s[pos] = tot;          // only thread `pos` reads s[pos] afterwards (same wave)
  }
  __syncthreads();
  if (tid < 8) {
    int pd = tid >> 2, ph = (tid >> 1) & 1, pw = tid & 1;
    float m = -3.402823466e38f;
#pragma unroll
    for (int dd = 0; dd < 2; ++dd)
#pragma unroll
      for (int hh = 0; hh < 2; ++hh)
#pragma unroll
        for (int ww = 0; ww < 2; ++ww)
          m = fmaxf(m, s[(pd * 2 + dd) * 16 + (ph * 2 + hh) * 4 + (pw * 2 + ww)]);
    h1[(n * 128 + oc) * 8 + tid] = fmaxf(m, 0.0f);
  }
}

// ---------------- conv2 + bias + maxpool2 + relu + linear (atomic) ----------------
// grid 128 = 2n * 64oc, 64 threads = 8 icgroups x 8 pos
__global__ __launch_bounds__(64) void k_conv2(const float* __restrict__ h1,
                                              const float* __restrict__ w2,
                                              const float* __restrict__ b2,
                                              const float* __restrict__ lw,
                                              const float* __restrict__ lb,
                                              float* __restrict__ logits) {
  __shared__ float hl[1024];    // h1[n][128][8]
  __shared__ float wl[3456];    // w2[oc][128][27]
  __shared__ float red[64];
  int n = blockIdx.x >> 6, oc = blockIdx.x & 63;
  int tid = threadIdx.x;
  for (int i = tid; i < 1024; i += 64) hl[i] = h1[n * 1024 + i];
  for (int i = tid; i < 3456; i += 64) wl[i] = w2[oc * 3456 + i];
  __syncthreads();
  int p = tid & 7, g = tid >> 3;
  int d = p >> 2, h = (p >> 1) & 1, w = p & 1;
  float acc = 0.0f;
  for (int ic = g * 16; ic < g * 16 + 16; ++ic) {
#pragma unroll
    for (int a = 0; a < 2; ++a)
#pragma unroll
      for (int b = 0; b < 2; ++b)
#pragma unroll
        for (int c = 0; c < 2; ++c) {
          int tapi = (a - d + 1) * 9 + (b - h + 1) * 3 + (c - w + 1);
          acc += hl[ic * 8 + a * 4 + b * 2 + c] * wl[ic * 27 + tapi];
        }
  }
  red[tid] = acc;
  __syncthreads();
  if (tid == 0) {
    float mx = -3.402823466e38f;
#pragma unroll
    for (int pp = 0; pp < 8; ++pp) {
      float sv = b2[oc];
#pragma unroll
      for (int gg = 0; gg < 8; ++gg) sv += red[gg * 8 + pp];
      mx = fmaxf(mx, sv);
    }
    float h2v = fmaxf(mx, 0.0f);
    atomicAdd(&logits[n], h2v * lw[oc]);
    if (oc == 0) atomicAdd(&logits[n], lb[0]);
  }
}

extern "C" void kernel_launch(void* const* d_in, const int* in_sizes, int n_in,
                              void* d_out, int out_size, void* d_ws, size_t ws_size,
                              hipStream_t stream) {
  const float* feat  = (const float*)d_in[0];
  const int*   masks = (const int*)  d_in[1];
  const float* dom   = (const float*)d_in[2];
  const float* w1    = (const float*)d_in[3];
  const float* b1    = (const float*)d_in[4];
  const float* w2    = (const float*)d_in[5];
  const float* b2    = (const float*)d_in[6];
  const float* lw    = (const float*)d_in[7];
  const float* lb    = (const float*)d_in[8];
  float* out = (float*)d_out;
  float* ws  = (float*)d_ws;
  float* wt  = ws + WS_WT;
  float* P   = ws + WS_P;
  float* h1  = ws + WS_H1;
  float* logits = out + OUT_LOG;

  k_trans<<<128, 256, 0, stream>>>(w1, wt, logits);
  k_conv1<<<216, 256, 0, stream>>>(dom, wt, P);
  k_pool1<<<256, 256, 0, stream>>>(P, b1, h1);
  k_conv2<<<128, 64, 0, stream>>>(h1, w2, b2, lw, lb, logits);
  k_cam<<<1728, 1024, 0, stream>>>(feat, masks, out);
}